// Round 11
// baseline (62.437 us; speedup 1.0000x reference)
//
#include <hip/hip_runtime.h>

#define NN    4096
#define MM    8191   // 2*NN - 1
#define BB    256
#define CAP   256    // u16 slots per row (nnz/row ~41, max ~70)
#define NPART 512    // gather blocks -> partial-sum sets

__device__ __forceinline__ int prefix_lt(unsigned long long m) {
    return __builtin_amdgcn_mbcnt_hi((unsigned)(m >> 32),
           __builtin_amdgcn_mbcnt_lo((unsigned)m, 0u));
}

// round-to-nearest-even pack of two f32 into 2x bf16 in one uint
__device__ __forceinline__ unsigned pack2bf(float lo, float hi) {
    unsigned a = __float_as_uint(lo);
    unsigned b = __float_as_uint(hi);
    a += 0x7fffu + ((a >> 16) & 1u);
    b += 0x7fffu + ((b >> 16) & 1u);
    return (a >> 16) | (b & 0xffff0000u);
}

// ---------------------------------------------------------------------------
// k_prep: pack dd = bf16(d1 - d2) (2 MB). One float4/thread, 1024x256 grid.
// ---------------------------------------------------------------------------
__global__ __launch_bounds__(256) void k_prep(const float4* __restrict__ d1,
                                              const float4* __restrict__ d2,
                                              uint2* __restrict__ ddp) {
    int idx = blockIdx.x * 256 + threadIdx.x;
    float4 a = d1[idx], b = d2[idx];
    uint2 r;
    r.x = pack2bf(a.x - b.x, a.y - b.y);
    r.y = pack2bf(a.z - b.z, a.w - b.w);
    ddp[idx] = r;
}

// ---------------------------------------------------------------------------
// k_compact: one wave per ROW — measured AT the 6.2 TB/s stream roofline (R7).
// Two sequential 8-load halves per row; ballot+mbcnt compaction into
// per-wave u16 LDS buffer; direct cnt[m] store; uint4 writeout.
// ---------------------------------------------------------------------------
__global__ __launch_bounds__(256, 4) void k_compact(
        const float4* __restrict__ st4,
        int* __restrict__ cnt,
        unsigned short* __restrict__ list) {
    __shared__ unsigned short s_buf[4][CAP];
    const int wave = threadIdx.x >> 6;
    const int lane = threadIdx.x & 63;
    unsigned short* buf = s_buf[wave];
    const int m = blockIdx.x * 4 + wave;
    if (m >= MM) return;

    int c = 0;
    #pragma unroll
    for (int h = 0; h < 2; ++h) {
        const float4* base = st4 + (size_t)m * (NN / 4) + h * (NN / 8);
        float4 v0 = base[lane];
        float4 v1 = base[64  + lane];
        float4 v2 = base[128 + lane];
        float4 v3 = base[192 + lane];
        float4 v4 = base[256 + lane];
        float4 v5 = base[320 + lane];
        float4 v6 = base[384 + lane];
        float4 v7 = base[448 + lane];

        const int cb = h * (NN / 2);
        #define SITE(val, col)                                          \
        {                                                               \
            unsigned long long mk = __ballot((val) != 0.0f);            \
            if ((val) != 0.0f)                                          \
                buf[c + prefix_lt(mk)] = (unsigned short)(col);         \
            c += __popcll(mk);                                          \
        }
        #define QUAD(v, cb0)                                            \
            SITE(v.x, (cb0))     SITE(v.y, (cb0) + 1)                   \
            SITE(v.z, (cb0) + 2) SITE(v.w, (cb0) + 3)
        QUAD(v0, cb + (lane)       * 4)
        QUAD(v1, cb + (64  + lane) * 4)
        QUAD(v2, cb + (128 + lane) * 4)
        QUAD(v3, cb + (192 + lane) * 4)
        QUAD(v4, cb + (256 + lane) * 4)
        QUAD(v5, cb + (320 + lane) * 4)
        QUAD(v6, cb + (384 + lane) * 4)
        QUAD(v7, cb + (448 + lane) * 4)
        #undef QUAD
        #undef SITE
    }
    __builtin_amdgcn_wave_barrier();   // LDS writes before reads

    if (lane == 0) cnt[m] = c;
    uint4* lv = (uint4*)(list + (size_t)m * CAP);
    const int nv = (c + 7) >> 3;
    if (lane < nv) lv[lane] = ((const uint4*)buf)[lane];
}

// ---------------------------------------------------------------------------
// k_gather: NPART=512 blocks x 512 threads (8 waves), (512,4) -> 2 blocks/CU
// = 16 waves/CU. Wave gw = bid*8+wave owns rows m = gw + k*4096 (k=0,1),
// register accumulation across rows, LDS block reduction, then PLAIN stores
// to the block's private w1part slice — zero global atomics (R10 post-mortem:
// the residual 256-deep same-line atomic chain was ~8 us).
// ---------------------------------------------------------------------------
__global__ __launch_bounds__(512, 4) void k_gather(
        const uint2* __restrict__ ddp,
        const int* __restrict__ cnt,
        const unsigned short* __restrict__ list,
        const float* __restrict__ param,
        const int*   __restrict__ parents,
        float* __restrict__ w1part) {
    __shared__ unsigned long long s_listq[8][CAP / 4];   // 64 qwords/wave
    __shared__ float s_part[BB];
    const int tid  = threadIdx.x;
    const int wave = tid >> 6;
    const int lane = tid & 63;

    if (tid < BB) s_part[tid] = 0.0f;
    __syncthreads();

    float p0 = 0.f, p1 = 0.f, p2 = 0.f, p3 = 0.f;

    #define UNP0(u) __uint_as_float((u) << 16)
    #define UNP1(u) __uint_as_float((u) & 0xffff0000u)
    #define ACCA(g) { c0 += UNP0(g.x); c1 += UNP1(g.x); c2 += UNP0(g.y); c3 += UNP1(g.y); }
    #define ACCB(g) { e0 += UNP0(g.x); e1 += UNP1(g.x); e2 += UNP0(g.y); e3 += UNP1(g.y); }
    #pragma unroll
    for (int k = 0; k < 2; ++k) {
        const int m = blockIdx.x * 8 + wave + k * 4096;
        if (m >= MM) continue;
        int c = cnt[m];
        if (c > CAP) c = CAP;
        const unsigned long long* lsrc =
            (const unsigned long long*)(list + (size_t)m * CAP);
        s_listq[wave][lane] = lsrc[lane];
        __builtin_amdgcn_wave_barrier();
        const float wgt = param[parents[m]] - param[m];

        float c0 = 0.f, c1 = 0.f, c2 = 0.f, c3 = 0.f;
        float e0 = 0.f, e1 = 0.f, e2 = 0.f, e3 = 0.f;
        int i = 0;
        for (; i + 8 <= c; i += 8) {
            unsigned long long pk0 = s_listq[wave][i >> 2];
            unsigned long long pk1 = s_listq[wave][(i >> 2) + 1];
            unsigned o0 = (unsigned)( pk0        & 0xffffULL) * 64u + lane;
            unsigned o1 = (unsigned)((pk0 >> 16) & 0xffffULL) * 64u + lane;
            unsigned o2 = (unsigned)((pk0 >> 32) & 0xffffULL) * 64u + lane;
            unsigned o3 = (unsigned)((pk0 >> 48) & 0xffffULL) * 64u + lane;
            unsigned o4 = (unsigned)( pk1        & 0xffffULL) * 64u + lane;
            unsigned o5 = (unsigned)((pk1 >> 16) & 0xffffULL) * 64u + lane;
            unsigned o6 = (unsigned)((pk1 >> 32) & 0xffffULL) * 64u + lane;
            unsigned o7 = (unsigned)((pk1 >> 48) & 0xffffULL) * 64u + lane;
            uint2 g0 = ddp[o0];
            uint2 g1 = ddp[o1];
            uint2 g2 = ddp[o2];
            uint2 g3 = ddp[o3];
            uint2 g4 = ddp[o4];
            uint2 g5 = ddp[o5];
            uint2 g6 = ddp[o6];
            uint2 g7 = ddp[o7];
            ACCA(g0) ACCB(g1) ACCA(g2) ACCB(g3)
            ACCA(g4) ACCB(g5) ACCA(g6) ACCB(g7)
        }
        for (; i + 4 <= c; i += 4) {
            unsigned long long pk = s_listq[wave][i >> 2];
            unsigned o0 = (unsigned)( pk        & 0xffffULL) * 64u + lane;
            unsigned o1 = (unsigned)((pk >> 16) & 0xffffULL) * 64u + lane;
            unsigned o2 = (unsigned)((pk >> 32) & 0xffffULL) * 64u + lane;
            unsigned o3 = (unsigned)((pk >> 48) & 0xffffULL) * 64u + lane;
            uint2 g0 = ddp[o0];
            uint2 g1 = ddp[o1];
            uint2 g2 = ddp[o2];
            uint2 g3 = ddp[o3];
            ACCA(g0) ACCB(g1) ACCA(g2) ACCB(g3)
        }
        for (; i < c; ++i) {
            unsigned n = (unsigned)((s_listq[wave][i >> 2] >> ((i & 3) * 16)) & 0xffffULL);
            uint2 g = ddp[n * 64u + lane];
            ACCA(g)
        }
        p0 += wgt * fabsf(c0 + e0);
        p1 += wgt * fabsf(c1 + e1);
        p2 += wgt * fabsf(c2 + e2);
        p3 += wgt * fabsf(c3 + e3);
        __builtin_amdgcn_wave_barrier();   // list reads done before next k's writes
    }
    #undef ACCA
    #undef ACCB
    #undef UNP0
    #undef UNP1

    atomicAdd(&s_part[4 * lane + 0], p0);
    atomicAdd(&s_part[4 * lane + 1], p1);
    atomicAdd(&s_part[4 * lane + 2], p2);
    atomicAdd(&s_part[4 * lane + 3], p3);
    __syncthreads();
    if (tid < BB) w1part[(size_t)blockIdx.x * BB + tid] = s_part[tid];
}

// ---------------------------------------------------------------------------
// k_finalize: w1[b] = sum_j w1part[j*256+b] (512 KB, L2-hot, coalesced,
// 8-deep); out = sum_b (ot[b] - 0.5*w1[b])^2.
// ---------------------------------------------------------------------------
__global__ __launch_bounds__(256) void k_finalize(const float* __restrict__ w1part,
                                                  const float* __restrict__ ot,
                                                  float* __restrict__ out) {
    __shared__ float s[4];
    int tid = threadIdx.x;
    float a0 = 0.f, a1 = 0.f, a2 = 0.f, a3 = 0.f;
    float a4 = 0.f, a5 = 0.f, a6 = 0.f, a7 = 0.f;
    #pragma unroll 4
    for (int j = 0; j < NPART; j += 8) {
        a0 += w1part[(j    ) * BB + tid];
        a1 += w1part[(j + 1) * BB + tid];
        a2 += w1part[(j + 2) * BB + tid];
        a3 += w1part[(j + 3) * BB + tid];
        a4 += w1part[(j + 4) * BB + tid];
        a5 += w1part[(j + 5) * BB + tid];
        a6 += w1part[(j + 6) * BB + tid];
        a7 += w1part[(j + 7) * BB + tid];
    }
    float w1 = ((a0 + a1) + (a2 + a3)) + ((a4 + a5) + (a6 + a7));
    float e = ot[tid] - 0.5f * w1;
    float v = e * e;
    #pragma unroll
    for (int off = 32; off > 0; off >>= 1) v += __shfl_down(v, off, 64);
    if ((tid & 63) == 0) s[tid >> 6] = v;
    __syncthreads();
    if (tid == 0) out[0] = (s[0] + s[1]) + (s[2] + s[3]);
}

// ---------------------------------------------------------------------------
extern "C" void kernel_launch(void* const* d_in, const int* in_sizes, int n_in,
                              void* d_out, int out_size, void* d_ws, size_t ws_size,
                              hipStream_t stream) {
    const float* d1      = (const float*)d_in[0];
    const float* d2      = (const float*)d_in[1];
    const float* ot      = (const float*)d_in[2];
    const float* subtree = (const float*)d_in[3];
    const float* param   = (const float*)d_in[4];
    const int*   parents = (const int*)d_in[5];

    char* wsb = (char*)d_ws;
    int*   cnt = (int*)wsb;                               // MM ints
    size_t off = ((size_t)MM * 4 + 15) & ~(size_t)15;

    unsigned short* list = (unsigned short*)(wsb + off);  // MM*CAP u16 ~4.2 MB
    size_t ddoff = (off + (size_t)MM * CAP * 2 + 15) & ~(size_t)15;
    uint2* ddp = (uint2*)(wsb + ddoff);                   // 2 MB packed bf16
    size_t poff = ddoff + (size_t)NN * BB * 2;
    float* w1part = (float*)(wsb + poff);                 // NPART*BB f = 512 KB

    k_prep<<<1024, 256, 0, stream>>>((const float4*)d1, (const float4*)d2, ddp);
    k_compact<<<2048, 256, 0, stream>>>((const float4*)subtree, cnt, list);
    k_gather<<<NPART, 512, 0, stream>>>(ddp, cnt, list, param, parents, w1part);
    k_finalize<<<1, 256, 0, stream>>>(w1part, ot, (float*)d_out);
}

// Round 12
// 48.677 us; speedup vs baseline: 1.2827x; 1.2827x over previous
//
#include <hip/hip_runtime.h>

#define NN    4096
#define MM    8191   // 2*NN - 1
#define BB    256
#define CAP   256    // u16 slots per row (nnz/row ~41, max ~70)

__device__ __forceinline__ int prefix_lt(unsigned long long m) {
    return __builtin_amdgcn_mbcnt_hi((unsigned)(m >> 32),
           __builtin_amdgcn_mbcnt_lo((unsigned)m, 0u));
}

// round-to-nearest-even pack of two f32 into 2x bf16 in one uint
__device__ __forceinline__ unsigned pack2bf(float lo, float hi) {
    unsigned a = __float_as_uint(lo);
    unsigned b = __float_as_uint(hi);
    a += 0x7fffu + ((a >> 16) & 1u);
    b += 0x7fffu + ((b >> 16) & 1u);
    return (a >> 16) | (b & 0xffff0000u);
}

// ---------------------------------------------------------------------------
// k_prep: zero part2[256*256]; pack dd = bf16(d1-d2) (2 MB). One uint2/thread.
// ---------------------------------------------------------------------------
__global__ __launch_bounds__(256) void k_prep(const float4* __restrict__ d1,
                                              const float4* __restrict__ d2,
                                              float* __restrict__ part2,
                                              uint2* __restrict__ ddp) {
    int idx = blockIdx.x * 256 + threadIdx.x;          // 0..262143
    if (idx < 256 * BB) part2[idx] = 0.0f;
    float4 a = d1[idx], b = d2[idx];
    uint2 r;
    r.x = pack2bf(a.x - b.x, a.y - b.y);
    r.y = pack2bf(a.z - b.z, a.w - b.w);
    ddp[idx] = r;
}

// ---------------------------------------------------------------------------
// k_fused: one wave per ROW. Phase 1: scan the row (2 halves x 8 float4, the
// exact pattern that measured 6.2 TB/s in R7) with ballot+mbcnt compaction
// into a per-wave LDS u16 list. Phase 2: immediately gather from the 2 MB
// L2-resident bf16 dd, 8-deep. Across 16 waves/CU the scan HBM-waits and
// gather L2-rounds interleave -> fused ~ max(21,20) us instead of 21+20.
// Partials: LDS block-reduce, then depth-8 global atomicAdd into part2.
// ---------------------------------------------------------------------------
__global__ __launch_bounds__(256, 4) void k_fused(
        const float4* __restrict__ st4,
        const uint2* __restrict__ ddp,
        const float* __restrict__ param,
        const int*   __restrict__ parents,
        float* __restrict__ part2) {
    __shared__ unsigned short s_idx[4][CAP];   // per-wave index list (2 KB)
    __shared__ float s_part[BB];
    const int tid  = threadIdx.x;
    const int wave = tid >> 6;
    const int lane = tid & 63;
    unsigned short* buf = s_idx[wave];

    s_part[tid] = 0.0f;
    __syncthreads();

    const int m = blockIdx.x * 4 + wave;
    if (m < MM) {
        // ---- Phase 1: scan + compact -------------------------------------
        int c = 0;
        #pragma unroll
        for (int h = 0; h < 2; ++h) {
            const float4* base = st4 + (size_t)m * (NN / 4) + h * (NN / 8);
            float4 v0 = base[lane];
            float4 v1 = base[64  + lane];
            float4 v2 = base[128 + lane];
            float4 v3 = base[192 + lane];
            float4 v4 = base[256 + lane];
            float4 v5 = base[320 + lane];
            float4 v6 = base[384 + lane];
            float4 v7 = base[448 + lane];

            const int cb = h * (NN / 2);
            #define SITE(val, col)                                          \
            {                                                               \
                unsigned long long mk = __ballot((val) != 0.0f);            \
                if ((val) != 0.0f)                                          \
                    buf[c + prefix_lt(mk)] = (unsigned short)(col);         \
                c += __popcll(mk);                                          \
            }
            #define QUAD(v, cb0)                                            \
                SITE(v.x, (cb0))     SITE(v.y, (cb0) + 1)                   \
                SITE(v.z, (cb0) + 2) SITE(v.w, (cb0) + 3)
            QUAD(v0, cb + (lane)       * 4)
            QUAD(v1, cb + (64  + lane) * 4)
            QUAD(v2, cb + (128 + lane) * 4)
            QUAD(v3, cb + (192 + lane) * 4)
            QUAD(v4, cb + (256 + lane) * 4)
            QUAD(v5, cb + (320 + lane) * 4)
            QUAD(v6, cb + (384 + lane) * 4)
            QUAD(v7, cb + (448 + lane) * 4)
            #undef QUAD
            #undef SITE
        }
        __builtin_amdgcn_wave_barrier();   // LDS list writes before reads

        // ---- Phase 2: gather, 8-deep -------------------------------------
        float c0 = 0.f, c1 = 0.f, c2 = 0.f, c3 = 0.f;
        float e0 = 0.f, e1 = 0.f, e2 = 0.f, e3 = 0.f;
        #define UNP0(u) __uint_as_float((u) << 16)
        #define UNP1(u) __uint_as_float((u) & 0xffff0000u)
        #define ACCA(g) { c0 += UNP0(g.x); c1 += UNP1(g.x); c2 += UNP0(g.y); c3 += UNP1(g.y); }
        #define ACCB(g) { e0 += UNP0(g.x); e1 += UNP1(g.x); e2 += UNP0(g.y); e3 += UNP1(g.y); }
        const unsigned* lw = (const unsigned*)buf;
        int i = 0;
        for (; i + 8 <= c; i += 8) {
            unsigned q0 = lw[(i >> 1)    ];
            unsigned q1 = lw[(i >> 1) + 1];
            unsigned q2 = lw[(i >> 1) + 2];
            unsigned q3 = lw[(i >> 1) + 3];
            unsigned o0 = (q0 & 0xffffu) * 64u + lane;
            unsigned o1 = (q0 >> 16)     * 64u + lane;
            unsigned o2 = (q1 & 0xffffu) * 64u + lane;
            unsigned o3 = (q1 >> 16)     * 64u + lane;
            unsigned o4 = (q2 & 0xffffu) * 64u + lane;
            unsigned o5 = (q2 >> 16)     * 64u + lane;
            unsigned o6 = (q3 & 0xffffu) * 64u + lane;
            unsigned o7 = (q3 >> 16)     * 64u + lane;
            uint2 g0 = ddp[o0];
            uint2 g1 = ddp[o1];
            uint2 g2 = ddp[o2];
            uint2 g3 = ddp[o3];
            uint2 g4 = ddp[o4];
            uint2 g5 = ddp[o5];
            uint2 g6 = ddp[o6];
            uint2 g7 = ddp[o7];
            ACCA(g0) ACCB(g1) ACCA(g2) ACCB(g3)
            ACCA(g4) ACCB(g5) ACCA(g6) ACCB(g7)
        }
        for (; i + 4 <= c; i += 4) {
            unsigned q0 = lw[(i >> 1)    ];
            unsigned q1 = lw[(i >> 1) + 1];
            unsigned o0 = (q0 & 0xffffu) * 64u + lane;
            unsigned o1 = (q0 >> 16)     * 64u + lane;
            unsigned o2 = (q1 & 0xffffu) * 64u + lane;
            unsigned o3 = (q1 >> 16)     * 64u + lane;
            uint2 g0 = ddp[o0];
            uint2 g1 = ddp[o1];
            uint2 g2 = ddp[o2];
            uint2 g3 = ddp[o3];
            ACCA(g0) ACCB(g1) ACCA(g2) ACCB(g3)
        }
        for (; i < c; ++i) {
            unsigned n = buf[i];
            uint2 g = ddp[n * 64u + lane];
            ACCA(g)
        }
        #undef ACCA
        #undef ACCB
        #undef UNP0
        #undef UNP1

        const float wgt = param[parents[m]] - param[m];
        atomicAdd(&s_part[4 * lane + 0], wgt * fabsf(c0 + e0));
        atomicAdd(&s_part[4 * lane + 1], wgt * fabsf(c1 + e1));
        atomicAdd(&s_part[4 * lane + 2], wgt * fabsf(c2 + e2));
        atomicAdd(&s_part[4 * lane + 3], wgt * fabsf(c3 + e3));
    }
    __syncthreads();
    // depth-8 atomic chains on 256 distinct partial rows (~0.3 us, R10 model)
    atomicAdd(&part2[(size_t)(blockIdx.x & 255) * BB + tid], s_part[tid]);
}

// ---------------------------------------------------------------------------
// k_finalize: 1024 threads. Thread (s,b)=(tid>>8,tid&255) sums 64 of the 256
// part2 rows 8-deep (8 rounds); LDS-reduce the 4 s-slices; then
// out = sum_b (ot[b] - 0.5*w1[b])^2 via shuffle reduce.
// ---------------------------------------------------------------------------
__global__ __launch_bounds__(1024) void k_finalize(const float* __restrict__ part2,
                                                   const float* __restrict__ ot,
                                                   float* __restrict__ out) {
    __shared__ float s_red[4][BB];
    __shared__ float s_sq[16];
    const int tid = threadIdx.x;
    const int s = tid >> 8, b = tid & 255;

    float a0 = 0.f, a1 = 0.f, a2 = 0.f, a3 = 0.f;
    float a4 = 0.f, a5 = 0.f, a6 = 0.f, a7 = 0.f;
    #pragma unroll
    for (int j = 0; j < 64; j += 8) {
        int row = s * 64 + j;
        a0 += part2[(row    ) * BB + b];
        a1 += part2[(row + 1) * BB + b];
        a2 += part2[(row + 2) * BB + b];
        a3 += part2[(row + 3) * BB + b];
        a4 += part2[(row + 4) * BB + b];
        a5 += part2[(row + 5) * BB + b];
        a6 += part2[(row + 6) * BB + b];
        a7 += part2[(row + 7) * BB + b];
    }
    s_red[s][b] = ((a0 + a1) + (a2 + a3)) + ((a4 + a5) + (a6 + a7));
    __syncthreads();

    float v = 0.0f;
    if (s == 0) {
        float w1 = (s_red[0][b] + s_red[1][b]) + (s_red[2][b] + s_red[3][b]);
        float e = ot[b] - 0.5f * w1;
        v = e * e;
    }
    #pragma unroll
    for (int off = 32; off > 0; off >>= 1) v += __shfl_down(v, off, 64);
    if ((tid & 63) == 0) s_sq[tid >> 6] = v;
    __syncthreads();
    if (tid == 0) out[0] = (s_sq[0] + s_sq[1]) + (s_sq[2] + s_sq[3]);
}

// ---------------------------------------------------------------------------
extern "C" void kernel_launch(void* const* d_in, const int* in_sizes, int n_in,
                              void* d_out, int out_size, void* d_ws, size_t ws_size,
                              hipStream_t stream) {
    const float* d1      = (const float*)d_in[0];
    const float* d2      = (const float*)d_in[1];
    const float* ot      = (const float*)d_in[2];
    const float* subtree = (const float*)d_in[3];
    const float* param   = (const float*)d_in[4];
    const int*   parents = (const int*)d_in[5];

    char* wsb = (char*)d_ws;
    float* part2 = (float*)wsb;                         // 256*256 f = 256 KB
    uint2* ddp   = (uint2*)(wsb + 256 * BB * 4);        // 2 MB packed bf16

    k_prep<<<1024, 256, 0, stream>>>((const float4*)d1, (const float4*)d2,
                                     part2, ddp);
    k_fused<<<2048, 256, 0, stream>>>((const float4*)subtree, ddp,
                                      param, parents, part2);
    k_finalize<<<1, 1024, 0, stream>>>(part2, ot, (float*)d_out);
}